// Round 4
// baseline (205.045 us; speedup 1.0000x reference)
//
#include <hip/hip_runtime.h>

#define NNODE 2048
#define DD    512
#define HHID  256
#define LLAT  16
#define H2    32   // 2L

typedef __attribute__((ext_vector_type(8))) short  short8;
typedef __attribute__((ext_vector_type(4))) float  f32x4;

__device__ __forceinline__ unsigned short f2bf(float x) {
    unsigned int u = __float_as_uint(x);
    unsigned int r = (u + 0x7fffu + ((u >> 16) & 1u)) >> 16;  // RNE
    return (unsigned short)r;
}
__device__ __forceinline__ float bf2f(unsigned short u) {
    return __uint_as_float(((unsigned int)u) << 16);
}
// agent-scope (device-coherent) publish/consume — bypasses non-coherent XCD L2
__device__ __forceinline__ void stg_agent(float* p, float v) {
    __hip_atomic_store(p, v, __ATOMIC_RELAXED, __HIP_MEMORY_SCOPE_AGENT);
}
__device__ __forceinline__ float ldg_agent(const float* p) {
    return __hip_atomic_load(p, __ATOMIC_RELAXED, __HIP_MEMORY_SCOPE_AGENT);
}

// ---------------- T0: convert A, X, W1 to bf16; zero split-K counters ------------
__global__ __launch_bounds__(256) void t0_cvt(const float* __restrict__ A,
                                              const float* __restrict__ X,
                                              const float* __restrict__ W1,
                                              unsigned short* __restrict__ Abf,
                                              unsigned short* __restrict__ Xbf,
                                              unsigned short* __restrict__ W1bf,
                                              unsigned int* __restrict__ cnt) {
    // 288 counters total: t1 uses [0,128), t2 uses [128,256), t4 uses [256,288).
    // blockDim is 256, so cover the tail with a second guarded store
    // (R2/R3 bug: 'tid < 320' left [256,288) as poison -> t4 epilogue never ran).
    if (blockIdx.x == 0) {
        cnt[threadIdx.x] = 0u;
        if (threadIdx.x < 32) cnt[256 + threadIdx.x] = 0u;
    }
    const int NT = 1343488;   // 1048576 (A) + 262144 (X) + 32768 (W1) float4 units
    for (int v = blockIdx.x * 256 + threadIdx.x; v < NT; v += gridDim.x * 256) {
        const float* src; unsigned short* dst; int off;
        if (v < 1048576)      { src = A;  dst = Abf;  off = v; }
        else if (v < 1310720) { src = X;  dst = Xbf;  off = v - 1048576; }
        else                  { src = W1; dst = W1bf; off = v - 1310720; }
        float4 f = ((const float4*)src)[off];
        short4 h;
        h.x = (short)f2bf(f.x); h.y = (short)f2bf(f.y);
        h.z = (short)f2bf(f.z); h.w = (short)f2bf(f.w);
        ((short4*)dst)[off] = h;
    }
}

// ------- T1f: XWp[s] = partial W1bf @ Xbf^T (splitK=4); last block -> XWt bf16 ---
__global__ __launch_bounds__(256) void t1f(const unsigned short* __restrict__ W1bf,
                                           const unsigned short* __restrict__ Xbf,
                                           float* __restrict__ XWp,
                                           unsigned short* __restrict__ XWt,
                                           unsigned int* __restrict__ cnt) {
    __shared__ __align__(16) unsigned short Ab[64][40];
    __shared__ __align__(16) unsigned short Bb[64][40];
    __shared__ unsigned int lastf;
    const int tid = threadIdx.x;
    const int n0 = blockIdx.x * 64;
    const int h0 = blockIdx.y * 64;
    const int ks = blockIdx.z;          // 0..3, K chunk of 128
    const int lane = tid & 63, wave = tid >> 6;
    const int wm = wave >> 1, wn = wave & 1;
    const int lm = lane & 15, lk = (lane >> 4) * 8;
    const int sr = tid >> 2, sc = (tid & 3) * 8;
    f32x4 acc[2][2] = {};
    for (int it = 0; it < 4; ++it) {
        int kk = ks * 128 + it * 32;
        *(uint4*)&Ab[sr][sc] = *(const uint4*)(W1bf + (size_t)(h0 + sr) * DD + kk + sc);
        *(uint4*)&Bb[sr][sc] = *(const uint4*)(Xbf  + (size_t)(n0 + sr) * DD + kk + sc);
        __syncthreads();
        short8 a0 = *(const short8*)&Ab[wm * 32 + lm][lk];
        short8 a1 = *(const short8*)&Ab[wm * 32 + 16 + lm][lk];
        short8 b0 = *(const short8*)&Bb[wn * 32 + lm][lk];
        short8 b1 = *(const short8*)&Bb[wn * 32 + 16 + lm][lk];
        acc[0][0] = __builtin_amdgcn_mfma_f32_16x16x32_bf16(a0, b0, acc[0][0], 0, 0, 0);
        acc[0][1] = __builtin_amdgcn_mfma_f32_16x16x32_bf16(a0, b1, acc[0][1], 0, 0, 0);
        acc[1][0] = __builtin_amdgcn_mfma_f32_16x16x32_bf16(a1, b0, acc[1][0], 0, 0, 0);
        acc[1][1] = __builtin_amdgcn_mfma_f32_16x16x32_bf16(a1, b1, acc[1][1], 0, 0, 0);
        __syncthreads();
    }
    float* outp = XWp + (size_t)ks * 524288;
    #pragma unroll
    for (int mi = 0; mi < 2; ++mi)
        #pragma unroll
        for (int ni = 0; ni < 2; ++ni)
            #pragma unroll
            for (int r = 0; r < 4; ++r) {
                int row = h0 + wm * 32 + mi * 16 + (lane >> 4) * 4 + r;
                int col = n0 + wn * 32 + ni * 16 + lm;
                stg_agent(&outp[(size_t)row * NNODE + col], acc[mi][ni][r]);
            }
    // ---- last-block reduction: XWt = bf16(sum_s XWp[s]) for this 64x64 tile ----
    __syncthreads();
    if (tid == 0) {
        __threadfence();
        lastf = (atomicAdd(&cnt[blockIdx.y * 32 + blockIdx.x], 1u) == 3u) ? 1u : 0u;
    }
    __syncthreads();
    if (!lastf) return;
    __threadfence();
    const int rr = h0 + (tid >> 2);
    const int c0 = n0 + (tid & 3) * 16;
    const float* base = XWp + (size_t)rr * NNODE + c0;
    #pragma unroll
    for (int q = 0; q < 4; ++q) {
        float s4[4];
        #pragma unroll
        for (int e = 0; e < 4; ++e) {
            float a = ldg_agent(base + q * 4 + e);
            float b = ldg_agent(base + 524288 + q * 4 + e);
            float c = ldg_agent(base + 1048576 + q * 4 + e);
            float d = ldg_agent(base + 1572864 + q * 4 + e);
            s4[e] = (a + b) + (c + d);
        }
        short4 h;
        h.x = (short)f2bf(s4[0]); h.y = (short)f2bf(s4[1]);
        h.z = (short)f2bf(s4[2]); h.w = (short)f2bf(s4[3]);
        *(short4*)(XWt + (size_t)rr * NNODE + c0 + q * 4) = h;
    }
}

// ------- T2f: Hp[s] = partial A @ XW (splitK=4); last block -> leaky+bias+bf16 ---
__global__ __launch_bounds__(256) void t2f(const unsigned short* __restrict__ Abf,
                                           const unsigned short* __restrict__ XWt,
                                           float* __restrict__ Hp,
                                           const float* __restrict__ bias1,
                                           unsigned short* __restrict__ Hbf,
                                           unsigned int* __restrict__ cnt) {
    __shared__ __align__(16) unsigned short Ab[64][40];
    __shared__ __align__(16) unsigned short Bb[64][40];
    __shared__ unsigned int lastf;
    const int tid = threadIdx.x;
    const int m0 = blockIdx.x * 64;
    const int n0 = blockIdx.y * 64;
    const int ks = blockIdx.z;          // 0..3, K chunk of 512
    const int lane = tid & 63, wave = tid >> 6;
    const int wm = wave >> 1, wn = wave & 1;
    const int lm = lane & 15, lk = (lane >> 4) * 8;
    const int sr = tid >> 2, sc = (tid & 3) * 8;
    f32x4 acc[2][2] = {};
    for (int it = 0; it < 16; ++it) {
        int kk = ks * 512 + it * 32;
        *(uint4*)&Ab[sr][sc] = *(const uint4*)(Abf + (size_t)(m0 + sr) * NNODE + kk + sc);
        *(uint4*)&Bb[sr][sc] = *(const uint4*)(XWt + (size_t)(n0 + sr) * NNODE + kk + sc);
        __syncthreads();
        short8 a0 = *(const short8*)&Ab[wm * 32 + lm][lk];
        short8 a1 = *(const short8*)&Ab[wm * 32 + 16 + lm][lk];
        short8 b0 = *(const short8*)&Bb[wn * 32 + lm][lk];
        short8 b1 = *(const short8*)&Bb[wn * 32 + 16 + lm][lk];
        acc[0][0] = __builtin_amdgcn_mfma_f32_16x16x32_bf16(a0, b0, acc[0][0], 0, 0, 0);
        acc[0][1] = __builtin_amdgcn_mfma_f32_16x16x32_bf16(a0, b1, acc[0][1], 0, 0, 0);
        acc[1][0] = __builtin_amdgcn_mfma_f32_16x16x32_bf16(a1, b0, acc[1][0], 0, 0, 0);
        acc[1][1] = __builtin_amdgcn_mfma_f32_16x16x32_bf16(a1, b1, acc[1][1], 0, 0, 0);
        __syncthreads();
    }
    float* outp = Hp + (size_t)ks * 524288;
    #pragma unroll
    for (int mi = 0; mi < 2; ++mi)
        #pragma unroll
        for (int ni = 0; ni < 2; ++ni)
            #pragma unroll
            for (int r = 0; r < 4; ++r) {
                int row = m0 + wm * 32 + mi * 16 + (lane >> 4) * 4 + r;
                int col = n0 + wn * 32 + ni * 16 + lm;
                stg_agent(&outp[(size_t)row * HHID + col], acc[mi][ni][r]);
            }
    // ---- last-block: Hbf = bf16(leaky(sum_s Hp[s] + b1)) for this 64x64 tile ----
    __syncthreads();
    if (tid == 0) {
        __threadfence();
        lastf = (atomicAdd(&cnt[128 + blockIdx.y * 32 + blockIdx.x], 1u) == 3u) ? 1u : 0u;
    }
    __syncthreads();
    if (!lastf) return;
    __threadfence();
    const int rr = m0 + (tid >> 2);
    const int c0 = n0 + (tid & 3) * 16;
    const float* base = Hp + (size_t)rr * HHID + c0;
    #pragma unroll
    for (int q = 0; q < 4; ++q) {
        float s4[4];
        #pragma unroll
        for (int e = 0; e < 4; ++e) {
            float a = ldg_agent(base + q * 4 + e);
            float b = ldg_agent(base + 524288 + q * 4 + e);
            float c = ldg_agent(base + 1048576 + q * 4 + e);
            float d = ldg_agent(base + 1572864 + q * 4 + e);
            float s = (a + b) + (c + d) + bias1[c0 + q * 4 + e];
            s4[e] = fmaxf(s, 0.01f * s);
        }
        short4 h;
        h.x = (short)f2bf(s4[0]); h.y = (short)f2bf(s4[1]);
        h.z = (short)f2bf(s4[2]); h.w = (short)f2bf(s4[3]);
        *(short4*)(Hbf + (size_t)rr * HHID + c0 + q * 4) = h;
    }
}

// ---------------- T3: Gt[j][n] = bf16( sum_d Hbf[n][d] * Wcat[j][d] ) ------------
__global__ __launch_bounds__(256) void t3_g(const unsigned short* __restrict__ Hbf,
                                            const float* __restrict__ Wmu,
                                            const float* __restrict__ Wlv,
                                            unsigned short* __restrict__ Gt) {
    __shared__ float Hs[8][260];
    __shared__ float Ws[32][260];
    const int tid = threadIdx.x;
    const int n0 = blockIdx.x * 8;
    #pragma unroll
    for (int s = 0; s < 8; ++s) {
        int idx = tid + s * 256;            // float4 units, 0..2047
        int row = idx >> 6, c = (idx & 63) * 4;
        const float* src = (row < 16) ? (Wmu + (size_t)row * HHID)
                                      : (Wlv + (size_t)(row - 16) * HHID);
        *(float4*)&Ws[row][c] = *(const float4*)(src + c);
    }
    {
        int r = tid >> 5, seg = tid & 31;
        int d = seg * 8;
        ushort4 u0 = *(const ushort4*)(Hbf + (size_t)(n0 + r) * HHID + d);
        ushort4 u1 = *(const ushort4*)(Hbf + (size_t)(n0 + r) * HHID + d + 4);
        Hs[r][d + 0] = bf2f(u0.x); Hs[r][d + 1] = bf2f(u0.y);
        Hs[r][d + 2] = bf2f(u0.z); Hs[r][d + 3] = bf2f(u0.w);
        Hs[r][d + 4] = bf2f(u1.x); Hs[r][d + 5] = bf2f(u1.y);
        Hs[r][d + 6] = bf2f(u1.z); Hs[r][d + 7] = bf2f(u1.w);
    }
    __syncthreads();
    const int r = tid >> 5, j = tid & 31;
    float acc = 0.f;
    #pragma unroll 8
    for (int d4 = 0; d4 < 64; ++d4) {
        float4 a = *(const float4*)&Hs[r][d4 * 4];
        float4 b = *(const float4*)&Ws[j][d4 * 4];
        acc += a.x * b.x + a.y * b.y + a.z * b.z + a.w * b.w;
    }
    Gt[(size_t)j * NNODE + n0 + r] = f2bf(acc);
}

// ------- T4f: Mp[s] = partial A @ G (splitK=8); last block -> full T5 epilogue ---
__global__ __launch_bounds__(256) void t4f(const unsigned short* __restrict__ Abf,
                                           const unsigned short* __restrict__ Gt,
                                           float* __restrict__ Mp,
                                           unsigned int* __restrict__ cnt,
                                           const float* __restrict__ bmu,
                                           const float* __restrict__ blv,
                                           const float* __restrict__ eps,
                                           const float* __restrict__ Wd1,
                                           const float* __restrict__ bd1,
                                           const float* __restrict__ Wd2,
                                           float* __restrict__ out_mu,
                                           float* __restrict__ out_lv,
                                           float* __restrict__ Pp,
                                           float* __restrict__ Qq,
                                           float* __restrict__ WP,
                                           float* __restrict__ WQ) {
    __shared__ __align__(16) unsigned short Ab[64][40];
    __shared__ __align__(16) unsigned short Bb[32][40];
    __shared__ float Zs[64][16];
    __shared__ float Psh[64][32];
    __shared__ float Qsh[64][32];
    __shared__ unsigned int lastf;
    const int tid = threadIdx.x;
    const int m0 = blockIdx.x * 64;
    const int ks = blockIdx.y;          // 0..7, K chunk of 256
    const int lane = tid & 63, wave = tid >> 6;
    const int lm = lane & 15, lk = (lane >> 4) * 8;
    const int sr = tid >> 2, sc = (tid & 3) * 8;
    f32x4 acc[2] = {};
    for (int it = 0; it < 8; ++it) {
        int kk = ks * 256 + it * 32;
        *(uint4*)&Ab[sr][sc] = *(const uint4*)(Abf + (size_t)(m0 + sr) * NNODE + kk + sc);
        if (tid < 128) {
            int row = tid >> 2, c = (tid & 3) * 8;
            *(uint4*)&Bb[row][c] = *(const uint4*)(Gt + (size_t)row * NNODE + kk + c);
        }
        __syncthreads();
        short8 a  = *(const short8*)&Ab[wave * 16 + lm][lk];
        short8 b0 = *(const short8*)&Bb[lm][lk];
        short8 b1 = *(const short8*)&Bb[16 + lm][lk];
        acc[0] = __builtin_amdgcn_mfma_f32_16x16x32_bf16(a, b0, acc[0], 0, 0, 0);
        acc[1] = __builtin_amdgcn_mfma_f32_16x16x32_bf16(a, b1, acc[1], 0, 0, 0);
        __syncthreads();
    }
    float* outp = Mp + (size_t)ks * 65536;
    #pragma unroll
    for (int ni = 0; ni < 2; ++ni)
        #pragma unroll
        for (int r = 0; r < 4; ++r) {
            int row = m0 + wave * 16 + (lane >> 4) * 4 + r;
            int col = ni * 16 + lm;
            stg_agent(&outp[(size_t)row * H2 + col], acc[ni][r]);
        }
    // ---- last-block: reduce Mp; mu/logvar; Z; P,Q; WP/WQ for rows m0..m0+63 ----
    __syncthreads();
    if (tid == 0) {
        __threadfence();
        lastf = (atomicAdd(&cnt[256 + blockIdx.x], 1u) == 7u) ? 1u : 0u;
    }
    __syncthreads();
    if (!lastf) return;
    __threadfence();
    #pragma unroll
    for (int p = 0; p < 4; ++p) {
        int idx = tid + p * 256;            // 0..1023
        int nl = idx >> 4, l = idx & 15;
        int n = m0 + nl;
        float m = bmu[l], lv = blv[l];
        #pragma unroll
        for (int s = 0; s < 8; ++s) {
            m  += ldg_agent(&Mp[(size_t)s * 65536 + (size_t)n * H2 + l]);
            lv += ldg_agent(&Mp[(size_t)s * 65536 + (size_t)n * H2 + 16 + l]);
        }
        out_mu[(size_t)n * LLAT + l] = m;
        out_lv[(size_t)n * LLAT + l] = lv;
        Zs[nl][l] = m + eps[(size_t)n * LLAT + l] * __expf(0.5f * lv);
    }
    __syncthreads();
    #pragma unroll
    for (int p = 0; p < 8; ++p) {
        int idx = tid + p * 256;            // 0..2047
        int nl = idx >> 5, o = idx & 31;
        int n = m0 + nl;
        float ap = bd1[o], aq = 0.f;
        #pragma unroll
        for (int l = 0; l < 16; ++l) {
            float z = Zs[nl][l];
            ap = fmaf(z, Wd1[o * H2 + l],      ap);
            aq = fmaf(z, Wd1[o * H2 + 16 + l], aq);
        }
        Pp[(size_t)n * H2 + o] = ap;
        Qq[(size_t)n * H2 + o] = aq;
        Psh[nl][o] = ap;
        Qsh[nl][o] = aq;
    }
    __syncthreads();
    if (tid < 128) {
        int nl = tid & 63, sel = tid >> 6;
        float a = 0.f;
        if (sel == 0) {
            #pragma unroll
            for (int o = 0; o < 32; ++o) a = fmaf(Wd2[o], Psh[nl][o], a);
            WP[m0 + nl] = a;
        } else {
            #pragma unroll
            for (int o = 0; o < 32; ++o) a = fmaf(Wd2[o], Qsh[nl][o], a);
            WQ[m0 + nl] = a;
        }
    }
}

// ---------------- T6: decoder via leaky(x)=0.505x+0.495|x| decomposition ---------
__global__ __launch_bounds__(256) void t6_dec(const float* __restrict__ Pp,
                                              const float* __restrict__ Qq,
                                              const float* __restrict__ WP,
                                              const float* __restrict__ WQ,
                                              const float* __restrict__ Wd2,
                                              const float* __restrict__ bd2,
                                              float* __restrict__ Apred) {
    __shared__ float Qt[32][68];   // transposed Q tile, padded
    __shared__ float Ws2[32];
    __shared__ float WQs[64];
    const int tid = threadIdx.x;
    const int j0 = blockIdx.x * 64, i0 = blockIdx.y * 16;
    #pragma unroll
    for (int s = 0; s < 8; ++s) {
        int idx = tid + s * 256;            // 0..2047
        int j = idx >> 5, o = idx & 31;
        Qt[o][j] = Qq[(size_t)(j0 + j) * H2 + o];
    }
    if (tid < 32) Ws2[tid] = Wd2[tid];
    if (tid >= 64 && tid < 128) WQs[tid - 64] = WQ[j0 + tid - 64];
    const int i = i0 + (tid >> 4);
    const int jq = tid & 15;
    float p[32];
    const float4* P4 = (const float4*)(Pp + (size_t)i * H2);
    #pragma unroll
    for (int c = 0; c < 8; ++c) {
        float4 v = P4[c];
        p[c * 4] = v.x; p[c * 4 + 1] = v.y; p[c * 4 + 2] = v.z; p[c * 4 + 3] = v.w;
    }
    const float WPi = WP[i];
    __syncthreads();
    f32x4 acc = {0.f, 0.f, 0.f, 0.f};   // sum_o w*|P+Q|
    #pragma unroll
    for (int o = 0; o < 32; ++o) {
        float4 q = *(const float4*)&Qt[o][jq * 4];
        float w = Ws2[o], po = p[o];
        acc[0] = fmaf(w, fabsf(po + q.x), acc[0]);
        acc[1] = fmaf(w, fabsf(po + q.y), acc[1]);
        acc[2] = fmaf(w, fabsf(po + q.z), acc[2]);
        acc[3] = fmaf(w, fabsf(po + q.w), acc[3]);
    }
    float4 wq = *(const float4*)&WQs[jq * 4];
    const float base = fmaf(0.505f, WPi, bd2[0]);
    float4 r;
    float l0 = fmaf(0.505f, wq.x, fmaf(0.495f, acc[0], base));
    float l1 = fmaf(0.505f, wq.y, fmaf(0.495f, acc[1], base));
    float l2 = fmaf(0.505f, wq.z, fmaf(0.495f, acc[2], base));
    float l3 = fmaf(0.505f, wq.w, fmaf(0.495f, acc[3], base));
    r.x = 1.f / (1.f + __expf(-l0));
    r.y = 1.f / (1.f + __expf(-l1));
    r.z = 1.f / (1.f + __expf(-l2));
    r.w = 1.f / (1.f + __expf(-l3));
    *(float4*)(Apred + (size_t)i * NNODE + j0 + jq * 4) = r;
}

extern "C" void kernel_launch(void* const* d_in, const int* in_sizes, int n_in,
                              void* d_out, int out_size, void* d_ws, size_t ws_size,
                              hipStream_t stream) {
    const float* A   = (const float*)d_in[0];
    const float* X   = (const float*)d_in[1];
    const float* eps = (const float*)d_in[2];
    const float* W1  = (const float*)d_in[3];
    const float* b1  = (const float*)d_in[4];
    const float* Wmu = (const float*)d_in[5];
    const float* bmu = (const float*)d_in[6];
    const float* Wlv = (const float*)d_in[7];
    const float* blv = (const float*)d_in[8];
    const float* Wd1 = (const float*)d_in[9];
    const float* bd1 = (const float*)d_in[10];
    const float* Wd2 = (const float*)d_in[11];
    const float* bd2 = (const float*)d_in[12];
    float* out = (float*)d_out;
    char* ws = (char*)d_ws;

    // workspace carve (~32.4 MB), all buffers fully overwritten each call
    unsigned short* Abf  = (unsigned short*)(ws);               //  8,388,608
    unsigned short* Xbf  = (unsigned short*)(ws + 8388608);     //  2,097,152
    unsigned short* W1bf = (unsigned short*)(ws + 10485760);    //    262,144
    float*          XWp  = (float*)(ws + 10747904);             //  8,388,608 (4 x 2MB)
    unsigned short* XWt  = (unsigned short*)(ws + 19136512);    //  1,048,576
    float*          Hp   = (float*)(ws + 20185088);             //  8,388,608 (4 x 2MB)
    unsigned short* Hbf  = (unsigned short*)(ws + 28573696);    //  1,048,576
    unsigned short* Gt   = (unsigned short*)(ws + 29622272);    //    131,072
    float*          Mp   = (float*)(ws + 29753344);             //  2,097,152 (8 x 256KB)
    float*          Pp   = (float*)(ws + 31850496);             //    262,144
    float*          Qq   = (float*)(ws + 32112640);             //    262,144
    float*          WP   = (float*)(ws + 32374784);             //      8,192
    float*          WQ   = (float*)(ws + 32382976);             //      8,192
    unsigned int*   cnt  = (unsigned int*)(ws + 32391168);      //      1,152 (288 ctrs)

    float* out_mu = out + (size_t)NNODE * NNODE;
    float* out_lv = out_mu + NNODE * LLAT;

    t0_cvt<<<2048,           256, 0, stream>>>(A, X, W1, Abf, Xbf, W1bf, cnt);
    t1f   <<<dim3(32, 4, 4), 256, 0, stream>>>(W1bf, Xbf, XWp, XWt, cnt);
    t2f   <<<dim3(32, 4, 4), 256, 0, stream>>>(Abf, XWt, Hp, b1, Hbf, cnt);
    t3_g  <<<256,            256, 0, stream>>>(Hbf, Wmu, Wlv, Gt);
    t4f   <<<dim3(32, 8),    256, 0, stream>>>(Abf, Gt, Mp, cnt, bmu, blv, eps,
                                               Wd1, bd1, Wd2, out_mu, out_lv,
                                               Pp, Qq, WP, WQ);
    t6_dec<<<dim3(32, 128),  256, 0, stream>>>(Pp, Qq, WP, WQ, Wd2, bd2, out);
}